// Round 4
// baseline (4569.693 us; speedup 1.0000x reference)
//
#include <hip/hip_runtime.h>
#include <math.h>

#define DD 128
#define HH 256
#define NS 300
#define BB 512
#define NBLK 256   // rollout blocks (2 rows each)
#define TPB 512
#define NPO (301*64)

// Dynamic-LDS float offsets for k_rollout
#define OFF_W1Q   0        // 8192 float4 = 32768 floats: [k4][hj]
#define OFF_XS    32768    // [2][128]
#define OFF_HS    33024    // [2][256]
#define OFF_WV    33536    // [2][128]
#define OFF_P2    33792    // [2][2][256]
#define OFF_P4    34816    // [4][2][128]
#define OFF_PM3   35840    // 3 x [4][2][128]
#define OFF_NOI   38912    // [2][128] (general only)
#define OFF_NVS   39168    // [2][128] (general; aliased as uu after D3)
#define OFF_RED   39424    // 16
#define SMEM_FLOATS 39440
#define SMEM_BYTES (SMEM_FLOATS*4)

__device__ __forceinline__ float tsf(int t){ return (float)((double)t*(1.0/(double)NS)); }

__device__ __forceinline__ float wave_red(float v){
#pragma unroll
  for(int o=32;o>0;o>>=1) v += __shfl_down(v,o);
  return v;
}
__device__ __forceinline__ float fma4(float4 a, float4 b, float acc){
  acc = fmaf(a.x,b.x,acc); acc = fmaf(a.y,b.y,acc);
  acc = fmaf(a.z,b.z,acc); acc = fmaf(a.w,b.w,acc); return acc;
}

// ---- pre1: identity flag + (general) Gauss-Jordan inverse -> SIT = sigma^-T
__global__ __launch_bounds__(256) void k_pre1(
    const float* __restrict__ sigma,
    float* __restrict__ SIT, float* __restrict__ AUG, int* __restrict__ FLG)
{
  const int j = threadIdx.x;
  __shared__ int s_ok; __shared__ int s_p; __shared__ float s_fac[DD];
  if (j == 0) s_ok = 1;
  __syncthreads();
  bool ok = true;
  for (int idx = j; idx < DD*DD; idx += 256) {
    const int r = idx >> 7, c = idx & 127;
    if (sigma[idx] != (r==c ? 1.f : 0.f)) ok = false;
  }
  if (!ok) s_ok = 0;
  __syncthreads();
  const bool ident = (s_ok != 0);
  if (j == 0) *FLG = ident ? 1 : 0;
  if (ident) {
    for (int idx = j; idx < DD*DD; idx += 256) {
      const int r = idx >> 7, c = idx & 127;
      SIT[idx] = (r==c) ? 1.f : 0.f;
    }
    return;
  }
  for (int idx = j; idx < DD*256; idx += 256) {
    const int r = idx >> 8, c = idx & 255;
    AUG[idx] = (c < DD) ? sigma[r*DD + c] : ((c-DD)==r ? 1.f : 0.f);
  }
  __syncthreads();
  for (int c = 0; c < DD; ++c) {
    if (j == 0) {
      int p = c; float best = fabsf(AUG[c*256 + c]);
      for (int r2 = c+1; r2 < DD; ++r2) {
        const float v = fabsf(AUG[r2*256 + c]);
        if (v > best) { best = v; p = r2; }
      }
      s_p = p;
    }
    __syncthreads();
    const int p = s_p;
    if (p != c) {
      const float tmp = AUG[c*256 + j];
      AUG[c*256 + j] = AUG[p*256 + j];
      AUG[p*256 + j] = tmp;
    }
    __syncthreads();
    const float pd = AUG[c*256 + c];
    const float rowv = AUG[c*256 + j];
    __syncthreads();
    AUG[c*256 + j] = rowv / pd;
    if (j < DD) s_fac[j] = (j == c) ? 0.f : AUG[j*256 + c];
    __syncthreads();
    const float prj = AUG[c*256 + j];
    for (int r2 = 0; r2 < DD; ++r2) {
      if (r2 != c) AUG[r2*256 + j] -= s_fac[r2] * prj;
    }
    __syncthreads();
  }
  for (int idx = j; idx < DD*DD; idx += 256) {
    const int j2 = idx >> 7, k = idx & 127;
    SIT[idx] = AUG[k*256 + DD + j2];
  }
}

// ---- pre2: M2 rows (-A @ sigma^-T) + sigma^T rows
__global__ __launch_bounds__(256) void k_pre2(
    const float* __restrict__ A, const float* __restrict__ sigma,
    const float* __restrict__ SIT, const int* __restrict__ FLG,
    float* __restrict__ M2row, float* __restrict__ SG2row)
{
  const int g = blockIdx.x*256 + threadIdx.x;
  const int gs = gridDim.x*256;
  const bool ident = (*FLG != 0);
  for (int idx = g; idx < DD*DD; idx += gs) {
    const int i2 = idx >> 7, k = idx & 127;
    SG2row[idx] = sigma[k*DD + i2];
    float m;
    if (ident) m = -A[idx];
    else {
      float acc = 0.f;
      for (int j = 0; j < DD; ++j) acc = fmaf(A[i2*DD + j], SIT[j*DD + k], acc);
      m = -acc;
    }
    M2row[idx] = m;
  }
}

// ---- rollout: 256 blocks x 512 threads, 2 trajectories per block.
// W1 in LDS; W2/A/P in registers (128 invariant regs); M2 = -A when sigma==I.
__global__ __launch_bounds__(TPB) void k_rollout(
    const float* __restrict__ x0, const float* __restrict__ sigma,
    const float* __restrict__ W1, const float* __restrict__ b1,
    const float* __restrict__ W2, const float* __restrict__ b2,
    const float* __restrict__ noises,
    const float* __restrict__ Am, const float* __restrict__ Pm,
    const float* __restrict__ Qm,
    const float* __restrict__ M2row, const float* __restrict__ SG2row,
    const int* __restrict__ FLG,
    float* __restrict__ U, float* __restrict__ TL,
    float* __restrict__ TGT, float* __restrict__ WGT)
{
  extern __shared__ float sm[];
  float4* W1q = (float4*)(sm + OFF_W1Q);    // [k4*256 + hj]
  float*  xs  = sm + OFF_XS;                // [r*128 + i]
  float*  hs  = sm + OFF_HS;                // [r*256 + hj]
  float*  wv  = sm + OFF_WV;                // [r*128 + i]
  float*  p2  = sm + OFF_P2;                // [hg*512 + r*256 + hj]
  float*  p4  = sm + OFF_P4;                // [q*256 + r*128 + i]
  float*  pm3 = sm + OFF_PM3;               // pA | pP | pM
  float*  noi = sm + OFF_NOI;
  float*  nvu = sm + OFF_NVS;
  float*  red = sm + OFF_RED;
  float4* xs4 = (float4*)xs;
  float4* hs4 = (float4*)hs;
  float4* wv4 = (float4*)wv;
  float4* nvu4= (float4*)nvu;
  float4* noi4= (float4*)noi;
  float*  pA = pm3, *pP = pm3 + 1024, *pM = pm3 + 2048;

  const int tid = threadIdx.x;
  const int hj = tid & 255, hg = tid >> 8;   // layer-1 mapping
  const int i = tid & 127, q = tid >> 7;     // layer-2 / matvec mapping
  const int wid = tid >> 6;
  const int b0 = blockIdx.x * 2;
  const bool ident = (*FLG != 0);

  // --- prologue: LDS W1 (k-quads) + register weights
  for (int idx = tid; idx < 8192; idx += TPB) {
    const int k4 = idx >> 8, h = idx & 255;
    float4 w;
    w.x = W1[(4*k4 + 1)*HH + h];
    w.y = W1[(4*k4 + 2)*HH + h];
    w.z = W1[(4*k4 + 3)*HH + h];
    w.w = W1[(4*k4 + 4)*HH + h];
    W1q[idx] = w;
  }
  const float w1t = (hg == 0) ? W1[hj] : 0.f;
  const float b1c = b1[hj];
  const float b2i = b2[i];

  float4 w2r[16], ar[8], pr[8];
#pragma unroll
  for (int m = 0; m < 16; ++m) {
    const int k = q*64 + 4*m;
    w2r[m] = make_float4(W2[(k+0)*DD+i], W2[(k+1)*DD+i], W2[(k+2)*DD+i], W2[(k+3)*DD+i]);
  }
#pragma unroll
  for (int m = 0; m < 8; ++m) {
    ar[m] = *(const float4*)(Am + i*DD + q*32 + 4*m);
    pr[m] = *(const float4*)(Pm + i*DD + q*32 + 4*m);
  }
  if (tid < DD) { const float v = x0[tid]; xs[tid] = v; xs[128 + tid] = v; }

  float lwloc = 0.f;
  float u_reg = 0.f, nz = 0.f;

  for (int t = 0; t <= NS; ++t) {
    __syncthreads();                                   // [A] xs (and W1q) ready
    const float t0 = tsf(t);
    const float dt = tsf(t+1) - t0;
    const float sdt = sqrtf(dt);
    nz = 0.f;
    if (q < 2 && t < NS) {
      nz = noises[((size_t)t*BB + b0 + q)*DD + i];
      if (!ident) noi[q*128 + i] = nz;
    }
    // --- MLP layer 1: thread (hj, hg) half-dot, both rows
    float a0 = t0*w1t, a1 = t0*w1t;
#pragma unroll
    for (int m = 0; m < 16; ++m) {
      const float4 w  = W1q[(hg*16 + m)*256 + hj];
      const float4 x0v = xs4[hg*16 + m];
      const float4 x1v = xs4[32 + hg*16 + m];
      a0 = fma4(w, x0v, a0); a1 = fma4(w, x1v, a1);
    }
    p2[hg*512 + hj] = a0; p2[hg*512 + 256 + hj] = a1;
    __syncthreads();                                   // [B]
    {
      const int rr = tid >> 8, cc = tid & 255;
      hs[rr*256 + cc] = tanhf(p2[rr*256 + cc] + p2[512 + rr*256 + cc] + b1c);
    }
    __syncthreads();                                   // [C]
    // --- MLP layer 2: register weights, quarter-dot, both rows
    a0 = 0.f; a1 = 0.f;
#pragma unroll
    for (int m = 0; m < 16; ++m) {
      const float4 h0 = hs4[q*16 + m];
      const float4 h1 = hs4[64 + q*16 + m];
      a0 = fma4(w2r[m], h0, a0); a1 = fma4(w2r[m], h1, a1);
    }
    p4[q*256 + i] = a0; p4[q*256 + 128 + i] = a1;
    __syncthreads();                                   // [D]
    if (ident) {
      if (q < 2) {
        const float nv = p4[q*128 + i] + p4[256 + q*128 + i]
                       + p4[512 + q*128 + i] + p4[768 + q*128 + i] + b2i;
        u_reg = -nv;
        U[((size_t)t*BB + b0 + q)*DD + i] = u_reg;
        wv[q*128 + i] = sdt*nz + dt*u_reg;
      }
    } else {
      if (q < 2) {
        nvu[q*128 + i] = p4[q*128 + i] + p4[256 + q*128 + i]
                       + p4[512 + q*128 + i] + p4[768 + q*128 + i] + b2i;
      }
      __syncthreads();                                 // [D2]
      float s0 = 0.f, s1 = 0.f;
#pragma unroll
      for (int m = 0; m < 8; ++m) {
        const float4 gv = *(const float4*)(SG2row + i*DD + q*32 + 4*m);
        const float4 n0 = nvu4[q*8 + m];
        const float4 n1 = nvu4[32 + q*8 + m];
        s0 = fma4(gv, n0, s0); s1 = fma4(gv, n1, s1);
      }
      pA[q*256 + i] = s0; pA[q*256 + 128 + i] = s1;
      __syncthreads();                                 // [D3]
      if (q < 2) {
        u_reg = -(pA[q*128 + i] + pA[256 + q*128 + i]
                + pA[512 + q*128 + i] + pA[768 + q*128 + i]);
        nvu[q*128 + i] = u_reg;                        // now uu
        U[((size_t)t*BB + b0 + q)*DD + i] = u_reg;
        wv[q*128 + i] = sdt*nz + dt*u_reg;
      }
    }
    if (t == NS) break;
    __syncthreads();                                   // [E] wv (and uu) ready
    // --- matvecs: A@x, P@x, and (A@wv) [ident: M2@wv = -(A@wv)]
    {
      float aA0=0,aA1=0,aP0=0,aP1=0,aM0=0,aM1=0;
      if (ident) {
#pragma unroll
        for (int m = 0; m < 8; ++m) {
          const float4 x0v = xs4[q*8 + m];
          const float4 x1v = xs4[32 + q*8 + m];
          const float4 w0v = wv4[q*8 + m];
          const float4 w1v = wv4[32 + q*8 + m];
          aA0 = fma4(ar[m], x0v, aA0); aA1 = fma4(ar[m], x1v, aA1);
          aP0 = fma4(pr[m], x0v, aP0); aP1 = fma4(pr[m], x1v, aP1);
          aM0 = fma4(ar[m], w0v, aM0); aM1 = fma4(ar[m], w1v, aM1);
        }
        aM0 = -aM0; aM1 = -aM1;
      } else {
#pragma unroll
        for (int m = 0; m < 8; ++m) {
          const float4 mrv = *(const float4*)(M2row + i*DD + q*32 + 4*m);
          const float4 x0v = xs4[q*8 + m];
          const float4 x1v = xs4[32 + q*8 + m];
          const float4 w0v = wv4[q*8 + m];
          const float4 w1v = wv4[32 + q*8 + m];
          aA0 = fma4(ar[m], x0v, aA0); aA1 = fma4(ar[m], x1v, aA1);
          aP0 = fma4(pr[m], x0v, aP0); aP1 = fma4(pr[m], x1v, aP1);
          aM0 = fma4(mrv, w0v, aM0);   aM1 = fma4(mrv, w1v, aM1);
        }
      }
      pA[q*256 + i] = aA0; pA[q*256 + 128 + i] = aA1;
      pP[q*256 + i] = aP0; pP[q*256 + 128 + i] = aP1;
      pM[q*256 + i] = aM0; pM[q*256 + 128 + i] = aM1;
      if (!ident) {
        float su0=0,su1=0,sn0=0,sn1=0;
#pragma unroll
        for (int m = 0; m < 8; ++m) {
          const float4 sv = *(const float4*)(sigma + i*DD + q*32 + 4*m);
          const float4 u0 = nvu4[q*8 + m];
          const float4 u1 = nvu4[32 + q*8 + m];
          const float4 z0 = noi4[q*8 + m];
          const float4 z1 = noi4[32 + q*8 + m];
          su0 = fma4(sv,u0,su0); su1 = fma4(sv,u1,su1);
          sn0 = fma4(sv,z0,sn0); sn1 = fma4(sv,z1,sn1);
        }
        p2[q*256 + i] = su0; p2[q*256 + 128 + i] = su1;
        p4[q*256 + i] = sn0; p4[q*256 + 128 + i] = sn1;
      }
    }
    __syncthreads();                                   // [F]
    if (q < 2) {
      const float xo = xs[q*128 + i];
      const float xa = pA[q*128+i] + pA[256+q*128+i] + pA[512+q*128+i] + pA[768+q*128+i];
      const float yy = pP[q*128+i] + pP[256+q*128+i] + pP[512+q*128+i] + pP[768+q*128+i];
      const float mm = pM[q*128+i] + pM[256+q*128+i] + pM[512+q*128+i] + pM[768+q*128+i];
      float usv, nsv;
      if (ident) { usv = u_reg; nsv = nz; }
      else {
        usv = p2[q*128+i] + p2[256+q*128+i] + p2[512+q*128+i] + p2[768+q*128+i];
        nsv = p4[q*128+i] + p4[256+q*128+i] + p4[512+q*128+i] + p4[768+q*128+i];
      }
      TL[(size_t)(t+1)*(BB*DD) + (size_t)(b0 + q)*DD + i] = dt*yy + mm;
      xs[q*128 + i] = xo + (xa + usv)*dt + sdt*nsv;
      lwloc += sdt*u_reg*nz - dt*(0.5f*u_reg*u_reg + 0.5f*xo*yy);
    }
  }
  // --- epilogue: TGT = x_NS @ Q^T, WGT = exp(lw - 0.5 x^T Q x)
  {
    float g0 = 0.f, g1 = 0.f;
#pragma unroll
    for (int m = 0; m < 8; ++m) {
      const float4 qv  = *(const float4*)(Qm + i*DD + q*32 + 4*m);
      const float4 x0v = xs4[q*8 + m];
      const float4 x1v = xs4[32 + q*8 + m];
      g0 = fma4(qv, x0v, g0); g1 = fma4(qv, x1v, g1);
    }
    pA[q*256 + i] = g0; pA[q*256 + 128 + i] = g1;
  }
  __syncthreads();
  float qloc = 0.f;
  if (q < 2) {
    const float tt = pA[q*128+i] + pA[256+q*128+i] + pA[512+q*128+i] + pA[768+q*128+i];
    TGT[(b0 + q)*DD + i] = tt;
    qloc = xs[q*128 + i]*tt;
  }
  const float rq = wave_red(qloc);
  const float rl = wave_red(lwloc);
  if ((tid & 63) == 0) { red[wid] = rq; red[8 + wid] = rl; }
  __syncthreads();
  if (tid == 0 || tid == 128) {
    const int r = tid >> 7;
    const float qf = red[2*r] + red[2*r + 1];
    const float lw = red[8 + 2*r] + red[8 + 2*r + 1];
    WGT[b0 + r] = expf(lw - 0.5f*qf);
  }
}

// ---- suffix scan over t (64k independent scans) + fused objective (ident)
__global__ __launch_bounds__(256) void k_scan(
    const float* __restrict__ TGT, const float* __restrict__ WGT,
    const float* __restrict__ U, float* __restrict__ TL,
    const int* __restrict__ FLG, float* __restrict__ PART_S)
{
  const int tid = threadIdx.x;
  const int bi = blockIdx.x*256 + tid;
  const int b = bi >> 7;
  const bool id = (*FLG != 0);
  const float w = WGT[b];
  float lst = TGT[bi];
  float obj = 0.f;
  if (id) { const float d = lst + U[(size_t)NS*(BB*DD) + bi]; obj = w*d*d; }
#pragma unroll 4
  for (int t = NS; t >= 1; --t) {
    const float v = TL[(size_t)t*(BB*DD) + bi];
    if (!id) TL[(size_t)t*(BB*DD) + bi] = lst;
    lst += v;
    if (id) { const float d = lst + U[(size_t)(t-1)*(BB*DD) + bi]; obj += w*d*d; }
  }
  if (!id) TL[bi] = lst;
  __shared__ float r4[4];
  const float s = wave_red(obj);
  if ((tid & 63) == 0) r4[tid >> 6] = s;
  __syncthreads();
  if (tid == 0) PART_S[blockIdx.x] = id ? (r4[0]+r4[1]+r4[2]+r4[3]) : 0.f;
}

// ---- general-sigma objective (no-op when sigma == I)
__global__ __launch_bounds__(256) void k_obj(
    const float* __restrict__ SG2row, const float* __restrict__ TL,
    const float* __restrict__ U, const float* __restrict__ WGT,
    const int* __restrict__ FLG, float* __restrict__ PART_O)
{
  const int blk = blockIdx.x;
  if (*FLG != 0) { if (threadIdx.x == 0) PART_O[blk] = 0.f; return; }
  const int t = blk >> 6, bg = blk & 63;
  __shared__ __align__(16) float ls[8][132];
  __shared__ __align__(16) float us[8][128];
  __shared__ __align__(16) float pD[2][8][128];
  __shared__ float wg[8];
  __shared__ float r4[4];
  const int tid = threadIdx.x;
  const int i = tid & 127, h = tid >> 7;
  for (int idx = tid; idx < 8*128; idx += 256) {
    const int rr = idx >> 7, k = idx & 127;
    ls[rr][k] = TL[(size_t)t*(BB*DD) + (size_t)(bg*8+rr)*DD + k];
    us[rr][k] = U [(size_t)t*(BB*DD) + (size_t)(bg*8+rr)*DD + k];
  }
  if (tid < 8) wg[tid] = WGT[bg*8 + tid];
  __syncthreads();
  const float* grow = SG2row + i*DD + h*64;
#pragma unroll
  for (int rr = 0; rr < 8; ++rr) {
    float a = 0.f;
#pragma unroll
    for (int it = 0; it < 16; ++it) {
      float4 gv = *(const float4*)(grow + it*4);
      float4 l4 = *(const float4*)&ls[rr][h*64 + it*4];
      a = fma4(gv, l4, a);
    }
    pD[h][rr][i] = a;
  }
  __syncthreads();
  float obj = 0.f;
#pragma unroll
  for (int p = 0; p < 4; ++p) {
    const int rr = h*4 + p;
    const float d = pD[0][rr][i] + pD[1][rr][i] + us[rr][i];
    obj += wg[rr]*d*d;
  }
  const float s = wave_red(obj);
  if ((tid & 63) == 0) r4[tid >> 6] = s;
  __syncthreads();
  if (tid == 0) PART_O[blk] = r4[0]+r4[1]+r4[2]+r4[3];
}

__global__ __launch_bounds__(256) void k_fin(
    const float* __restrict__ PART_S, const float* __restrict__ PART_O,
    float* __restrict__ out)
{
  const int tid = threadIdx.x;
  float s = PART_S[tid];
  for (int idx = tid; idx < NPO; idx += 256) s += PART_O[idx];
  __shared__ float r4[4];
  const float v = wave_red(s);
  if ((tid & 63) == 0) r4[tid >> 6] = v;
  __syncthreads();
  if (tid == 0) out[0] = (r4[0]+r4[1]+r4[2]+r4[3]) * (1.0f/((float)(NS+1)*(float)BB));
}

extern "C" void kernel_launch(void* const* d_in, const int* in_sizes, int n_in,
                              void* d_out, int out_size, void* d_ws, size_t ws_size,
                              hipStream_t stream) {
  (void)in_sizes; (void)n_in; (void)out_size; (void)ws_size;
  const float* x0     = (const float*)d_in[0];
  const float* sigma  = (const float*)d_in[1];
  const float* A      = (const float*)d_in[2];
  const float* P      = (const float*)d_in[3];
  const float* Q      = (const float*)d_in[4];
  const float* W1     = (const float*)d_in[5];
  const float* b1     = (const float*)d_in[6];
  const float* W2     = (const float*)d_in[7];
  const float* b2     = (const float*)d_in[8];
  const float* noises = (const float*)d_in[9];

  float* ws = (float*)d_ws;
  const size_t SL = (size_t)BB*DD;
  float* TL     = ws;
  float* U      = TL + (size_t)(NS+1)*SL;
  float* TGT    = U  + (size_t)(NS+1)*SL;
  float* WGT    = TGT + SL;
  float* M2row  = WGT + BB;
  float* SG2row = M2row + (size_t)DD*DD;
  float* SIT    = SG2row + (size_t)DD*DD;
  float* AUG    = SIT + (size_t)DD*DD;
  float* PART_S = AUG + (size_t)DD*256;
  float* PART_O = PART_S + 256;
  int*   FLG    = (int*)(PART_O + NPO);
  float* out    = (float*)d_out;

  (void)hipFuncSetAttribute((const void*)k_rollout,
                            hipFuncAttributeMaxDynamicSharedMemorySize, SMEM_BYTES);

  k_pre1<<<1, 256, 0, stream>>>(sigma, SIT, AUG, FLG);
  k_pre2<<<32, 256, 0, stream>>>(A, sigma, SIT, FLG, M2row, SG2row);
  k_rollout<<<NBLK, TPB, SMEM_BYTES, stream>>>(x0, sigma, W1, b1, W2, b2, noises,
                                               A, P, Q, M2row, SG2row, FLG,
                                               U, TL, TGT, WGT);
  k_scan<<<(BB*DD)/256, 256, 0, stream>>>(TGT, WGT, U, TL, FLG, PART_S);
  k_obj<<<NPO, 256, 0, stream>>>(SG2row, TL, U, WGT, FLG, PART_O);
  k_fin<<<1, 256, 0, stream>>>(PART_S, PART_O, out);
}